// Round 6
// baseline (260.305 us; speedup 1.0000x reference)
//
#include <hip/hip_runtime.h>
#include <stdint.h>
#include <stddef.h>

// SNN autoencoder, fused. B=65536, D=512, H=64, L=16, T=8.
// Phase 1: h_in = x@W1^T + b1, pure-bf16 MFMA, register-direct fragments with
//          a DEPTH-3 UNIFORM-ORDER PREFETCH RING: per kc-slot, issue
//          [w1f x4, xa, xb] and consume oldest-first, so vmcnt waits always
//          leave >=2 slots (>=12 KB/wave) in flight. (Round-5 pathology: w1f
//          issued-last/consumed-first drained the x queue every window.)
// Phase A: closed-form spike test (v1(t)=h(1-2^-t) under constant drive ->
//          only rows with max_h h >= 1.0038 can ever spike); flagged rows
//          (~7%) run the exact stepwise sim. Wave-local, no __syncthreads.
// Phase B: s3 almost always all-zero -> out = sigmoid(b4) broadcast (exact);
//          rare spiking wave takes the bf16-MFMA + sigmoid path.

typedef __attribute__((ext_vector_type(8))) short bf16x8;   // 8 bf16 = 4 VGPRs
typedef __attribute__((ext_vector_type(4))) float f32x4;
typedef unsigned long long ull;

#define TS 8

__device__ __forceinline__ short f2bf(float f) {
  // round-to-nearest-even f32 -> bf16
  unsigned u = __float_as_uint(f);
  unsigned r = u + 0x7FFFu + ((u >> 16) & 1u);
  return (short)(r >> 16);
}

__device__ __forceinline__ float sigmoid_fast(float z) {
  float e = __builtin_amdgcn_exp2f(z * -1.44269504088896341f);
  return __builtin_amdgcn_rcpf(1.0f + e);
}

// ---- prep: W1[64][512] fp32 -> bf16 B-fragments in ws ----
// frag unit (nt, kc): 64 lanes x 8 shorts. Lane q=lane>>4, n=lane&15 holds
// W1[nt*16+n][kc*32 + q*8 + j], j=0..7.
__global__ __launch_bounds__(256) void w1_frag_prep(const float* __restrict__ W1,
                                                    short* __restrict__ ws) {
  const int g    = blockIdx.x * 256 + threadIdx.x;  // 0..4095
  const int lane = g & 63;
  const int idx  = g >> 6;                          // nt*16 + kc
  const int nt   = idx >> 4;
  const int kc   = idx & 15;
  const int n    = lane & 15;
  const int q    = lane >> 4;
  const float* wp = W1 + (size_t)(nt * 16 + n) * 512 + kc * 32 + q * 8;
  const float4 f0 = *(const float4*)wp;
  const float4 f1 = *(const float4*)(wp + 4);
  const float f[8] = {f0.x, f0.y, f0.z, f0.w, f1.x, f1.y, f1.z, f1.w};
  short* dst = ws + (size_t)g * 8;    // 16 B per lane
  #pragma unroll
  for (int j = 0; j < 8; j++) dst[j] = f2bf(f[j]);
}

__global__ __launch_bounds__(256, 4) void snn_fused(
    const float* __restrict__ x,  const short* __restrict__ w1f, const float* __restrict__ b1,
    const float* __restrict__ W2, const float* __restrict__ b2,
    const float* __restrict__ W3, const float* __restrict__ b3,
    const float* __restrict__ W4, const float* __restrict__ b4,
    float* __restrict__ out)
{
  __shared__ float hs[64 * 72];      // stride 72: 2-way bank alias = free
  __shared__ ull   masks[TS * 64];   // [t*64 + r], touched only on flagged path

  const int tid  = threadIdx.x;
  const int w    = tid >> 6;      // wave 0..3 <-> 16-row tile
  const int lane = tid & 63;
  const int rr   = lane >> 4;     // quad 0..3
  const int ll   = lane & 15;
  const int row0 = blockIdx.x * 64;

  // ================= Phase 1: h_in = x @ W1^T + b1 (bf16 MFMA) =============
  // A-frag: lane holds x[row0 + w*16 + ll][kc*32 + rr*8 + j], j=0..7.
  f32x4 acc[4];
  #pragma unroll
  for (int nt = 0; nt < 4; nt++) {
    const float bv = b1[nt * 16 + ll];
    f32x4 z = {bv, bv, bv, bv};
    acc[nt] = z;
  }

  const float* xrow = x + (size_t)(row0 + w * 16 + ll) * 512 + rr * 8;
  const short* wbase = w1f + (size_t)lane * 8;   // frag (nt,kc) at + (nt*16+kc)*512

  // depth-3 prefetch ring, strict issue order per slot: w1f x4, xa, xb
  bf16x8 bufW[3][4];
  float4 bufA[3], bufB[3];
  #pragma unroll
  for (int p = 0; p < 3; p++) {
    #pragma unroll
    for (int nt = 0; nt < 4; nt++)
      bufW[p][nt] = *(const bf16x8*)(wbase + (size_t)(nt * 16 + p) * 512);
    bufA[p] = *(const float4*)(xrow + p * 32);
    bufB[p] = *(const float4*)(xrow + p * 32 + 4);
  }

  #pragma unroll
  for (int kc = 0; kc < 16; kc++) {
    const int s = kc % 3;
    const float4 xa = bufA[s];
    const float4 xb = bufB[s];
    union { bf16x8 v; unsigned u4[4]; } A;
    A.u4[0] = __builtin_amdgcn_perm(__float_as_uint(xa.y), __float_as_uint(xa.x), 0x07060302u);
    A.u4[1] = __builtin_amdgcn_perm(__float_as_uint(xa.w), __float_as_uint(xa.z), 0x07060302u);
    A.u4[2] = __builtin_amdgcn_perm(__float_as_uint(xb.y), __float_as_uint(xb.x), 0x07060302u);
    A.u4[3] = __builtin_amdgcn_perm(__float_as_uint(xb.w), __float_as_uint(xb.z), 0x07060302u);
    #pragma unroll
    for (int nt = 0; nt < 4; nt++)
      acc[nt] = __builtin_amdgcn_mfma_f32_16x16x32_bf16(A.v, bufW[s][nt], acc[nt], 0, 0, 0);
    if (kc + 3 < 16) {
      #pragma unroll
      for (int nt = 0; nt < 4; nt++)
        bufW[s][nt] = *(const bf16x8*)(wbase + (size_t)(nt * 16 + kc + 3) * 512);
      bufA[s] = *(const float4*)(xrow + (kc + 3) * 32);
      bufB[s] = *(const float4*)(xrow + (kc + 3) * 32 + 4);
    }
  }
  // C layout: col = ll (h within nt-tile), row = rr*4 + e.

  // ============ Phase A: closed-form spike-possibility test ================
  // Stepwise v1(t) can reach 1 only if h >= (256/255)*(1-1e-6) > 1.0038.
  unsigned rowneed = 0;   // wave-uniform 16-bit: local row r flagged
  #pragma unroll
  for (int e = 0; e < 4; e++) {
    const float mx = fmaxf(fmaxf(acc[0][e], acc[1][e]), fmaxf(acc[2][e], acc[3][e]));
    const ull bal = __ballot(mx >= 1.0038f);
    #pragma unroll
    for (int r2 = 0; r2 < 4; r2++)
      if ((bal >> (r2 * 16)) & 0xFFFFu) rowneed |= 1u << (r2 * 4 + e);
  }

  ull s3any = 0;
  if (rowneed) {
    // stage h_in to LDS in lane=h layout (wave-local rows)
    #pragma unroll
    for (int nt = 0; nt < 4; nt++)
      #pragma unroll
      for (int e = 0; e < 4; e++)
        hs[(w * 16 + rr * 4 + e) * 72 + nt * 16 + ll] = acc[nt][e];
    // zero this wave's mask region (128 entries, 2 per lane)
    #pragma unroll
    for (int i = 0; i < 2; i++) {
      const int lin = i * 64 + lane;            // 0..127
      masks[(lin >> 4) * 64 + w * 16 + (lin & 15)] = 0ULL;
    }

    // weights for the sim
    float w2r[16], w3r[16];
    #pragma unroll
    for (int jj = 0; jj < 4; jj++) {
      const float4 t2 = *(const float4*)(W2 + ll * 64 + rr * 16 + jj * 4);
      w2r[jj * 4 + 0] = t2.x; w2r[jj * 4 + 1] = t2.y;
      w2r[jj * 4 + 2] = t2.z; w2r[jj * 4 + 3] = t2.w;
      const float4 t3 = *(const float4*)(W3 + lane * 16 + jj * 4);
      w3r[jj * 4 + 0] = t3.x; w3r[jj * 4 + 1] = t3.y;
      w3r[jj * 4 + 2] = t3.z; w3r[jj * 4 + 3] = t3.w;
    }
    const float b2r = b2[ll];
    const float b3r = b3[lane];

    unsigned rn = rowneed;
    while (rn) {
      const int r = __builtin_ctz(rn); rn &= rn - 1;
      const float h = hs[(w * 16 + r) * 72 + lane];   // lane = h index
      float v1 = 0.f, v2 = 0.f, v3 = 0.f;             // v2 replicated over quads
      for (int t = 0; t < TS; t++) {
        // --- LIF layer 1 (lane = h), exact stepwise ---
        v1 = v1 + (h - v1) * 0.5f;
        const bool s1 = v1 >= 1.0f;
        const ull m1 = __ballot(s1);
        if (s1) v1 = 0.f;
        // --- in2[l=ll] = b2 + sum_h s1[h]*W2[l][h], h split over quads ---
        float in2 = b2r;
        if (m1 != 0ULL) {
          const unsigned mb = (unsigned)(m1 >> (rr * 16)) & 0xFFFFu;
          float p = 0.f;
          #pragma unroll
          for (int j = 0; j < 16; j++) p += ((mb >> j) & 1u) ? w2r[j] : 0.f;
          p += __shfl_xor(p, 16);
          p += __shfl_xor(p, 32);
          in2 += p;
        }
        // --- LIF layer 2 (replicated across quads; ballot bits replicate) ---
        v2 = v2 + (in2 - v2) * 0.5f;
        const bool s2 = v2 >= 1.0f;
        const ull bm2 = __ballot(s2);
        if (s2) v2 = 0.f;
        const unsigned m2 = (unsigned)bm2 & 0xFFFFu;   // wave-uniform
        // --- in3[h=lane] = b3 + sum_l s2[l]*W3[h][l] ---
        float in3 = b3r;
        if (m2 != 0u) {
          float q = 0.f;
          #pragma unroll
          for (int j = 0; j < 16; j++) q += ((m2 >> j) & 1u) ? w3r[j] : 0.f;
          in3 += q;
        }
        // --- LIF layer 3 ---
        v3 = v3 + (in3 - v3) * 0.5f;
        const bool s3 = v3 >= 1.0f;
        const ull m3 = __ballot(s3);
        if (s3) v3 = 0.f;
        if (m3 != 0ULL) {
          if (lane == 0) masks[t * 64 + w * 16 + r] = m3;
          s3any |= m3;
        }
      }
    }
  }

  // ================= Phase B: out = mean_t sigmoid(s3 @ W4^T + b4) ==========
  if (s3any == 0ULL) {
    // Exact fast path: all s3 == 0 for this wave's 16 rows.
    const int cg = lane * 4;
    const float4 b4a = *(const float4*)(b4 + cg);
    const float4 b4b = *(const float4*)(b4 + 256 + cg);
    f32x4 sa, sb;
    sa[0] = sigmoid_fast(b4a.x); sa[1] = sigmoid_fast(b4a.y);
    sa[2] = sigmoid_fast(b4a.z); sa[3] = sigmoid_fast(b4a.w);
    sb[0] = sigmoid_fast(b4b.x); sb[1] = sigmoid_fast(b4b.y);
    sb[2] = sigmoid_fast(b4b.z); sb[3] = sigmoid_fast(b4b.w);
    #pragma unroll
    for (int r = 0; r < 16; r++) {
      float* rp = out + (size_t)(row0 + w * 16 + r) * 512;
      *(f32x4*)(rp + cg) = sa;
      *(f32x4*)(rp + 256 + cg) = sb;
    }
    return;
  }

  // ---- rare path: this wave's rows have s3 spikes; full MFMA over 512 cols ----
  for (int nt = 0; nt < 32; nt++) {
    const int dcol = nt * 16 + ll;
    const float bbv = b4[dcol];
    bf16x8 Bf[2];
    #pragma unroll
    for (int c = 0; c < 2; c++) {
      const float* wp = W4 + (size_t)dcol * 64 + c * 32 + rr * 8;
      const float4 f0 = *(const float4*)wp;
      const float4 f1 = *(const float4*)(wp + 4);
      union { bf16x8 v; short s[8]; } u;
      u.s[0] = f2bf(f0.x); u.s[1] = f2bf(f0.y); u.s[2] = f2bf(f0.z); u.s[3] = f2bf(f0.w);
      u.s[4] = f2bf(f1.x); u.s[5] = f2bf(f1.y); u.s[6] = f2bf(f1.z); u.s[7] = f2bf(f1.w);
      Bf[c] = u.v;
    }
    f32x4 accv = {0.f, 0.f, 0.f, 0.f};
    for (int t = 0; t < TS; t++) {
      // A[m][k]: m = ll (row in tile), k = c*32 + rr*8 + j -> bit k of row mask
      const ull mrow = masks[t * 64 + w * 16 + ll];
      const unsigned byte0 = (unsigned)(mrow >> (rr * 8)) & 0xFFu;
      const unsigned byte1 = (unsigned)((mrow >> 32) >> (rr * 8)) & 0xFFu;
      union { bf16x8 v; unsigned u4[4]; } a0, a1;
      #pragma unroll
      for (int p2 = 0; p2 < 4; p2++) {
        a0.u4[p2] = ((byte0 >> (2 * p2)) & 1u) * 0x3F80u
                  + ((byte0 >> (2 * p2 + 1)) & 1u) * 0x3F800000u;
        a1.u4[p2] = ((byte1 >> (2 * p2)) & 1u) * 0x3F80u
                  + ((byte1 >> (2 * p2 + 1)) & 1u) * 0x3F800000u;
      }
      f32x4 z = {bbv, bbv, bbv, bbv};
      z = __builtin_amdgcn_mfma_f32_16x16x32_bf16(a0.v, Bf[0], z, 0, 0, 0);
      z = __builtin_amdgcn_mfma_f32_16x16x32_bf16(a1.v, Bf[1], z, 0, 0, 0);
      #pragma unroll
      for (int e = 0; e < 4; e++) accv[e] += sigmoid_fast(z[e]);
    }
    #pragma unroll
    for (int e = 0; e < 4; e++) {
      const int rloc = w * 16 + rr * 4 + e;
      out[(size_t)(row0 + rloc) * 512 + dcol] = accv[e] * 0.125f;
    }
  }
}

extern "C" void kernel_launch(void* const* d_in, const int* in_sizes, int n_in,
                              void* d_out, int out_size, void* d_ws, size_t ws_size,
                              hipStream_t stream) {
  const float* x  = (const float*)d_in[0];
  const float* W1 = (const float*)d_in[1];
  const float* b1 = (const float*)d_in[2];
  const float* W2 = (const float*)d_in[3];
  const float* b2 = (const float*)d_in[4];
  const float* W3 = (const float*)d_in[5];
  const float* b3 = (const float*)d_in[6];
  const float* W4 = (const float*)d_in[7];
  const float* b4 = (const float*)d_in[8];
  float* out = (float*)d_out;
  short* w1f = (short*)d_ws;     // 4096 lanes * 8 shorts = 65536 B

  const int B = in_sizes[0] / 512;   // 65536
  const int nblocks = B / 64;        // 1024

  hipLaunchKernelGGL(w1_frag_prep, dim3(16), dim3(256), 0, stream, W1, w1f);
  hipLaunchKernelGGL(snn_fused, dim3(nblocks), dim3(256), 0, stream,
                     x, w1f, b1, W2, b2, W3, b3, W4, b4, out);
}

// Round 7
// 255.543 us; speedup vs baseline: 1.0186x; 1.0186x over previous
//
#include <hip/hip_runtime.h>
#include <stdint.h>
#include <stddef.h>

// SNN autoencoder, fused. B=65536, D=512, H=64, L=16, T=8.
// Phase 1: h_in = x@W1^T + b1 via bf16 MFMA with m97-style LDS DOUBLE BUFFER:
//          per K=64 chunk, issue next-chunk global loads, compute current
//          chunk from LDS, convert+write next buffer, ONE barrier. The
//          pipeline is enforced by the barrier structure (round-6 lesson:
//          register rings get re-scheduled away by the compiler).
// Phase A: closed-form spike test on accumulators (v1(t)=h(1-2^-t) =>
//          only rows with max_h h >= 1.0038 can ever spike). Flagged rows
//          (~7% of waves) run the exact stepwise sim; h fetched from acc via
//          ds_bpermute (no LDS array), spike masks kept in 2 ull registers.
// Phase B: s3 almost always all-zero -> out = sigmoid(b4) broadcast (exact);
//          rare spiking wave takes the bf16-MFMA + sigmoid path.

typedef __attribute__((ext_vector_type(8))) short bf16x8;   // 8 bf16 = 4 VGPRs
typedef __attribute__((ext_vector_type(4))) float f32x4;
typedef unsigned long long ull;

#define TS 8

__device__ __forceinline__ short f2bf(float f) {
  // round-to-nearest-even f32 -> bf16
  unsigned u = __float_as_uint(f);
  unsigned r = u + 0x7FFFu + ((u >> 16) & 1u);
  return (short)(r >> 16);
}

__device__ __forceinline__ unsigned packbf(float hi, float lo) {
  // truncate-pack two f32 to bf16x2 (lo in low half)
  return __builtin_amdgcn_perm(__float_as_uint(hi), __float_as_uint(lo), 0x07060302u);
}

__device__ __forceinline__ float sigmoid_fast(float z) {
  float e = __builtin_amdgcn_exp2f(z * -1.44269504088896341f);
  return __builtin_amdgcn_rcpf(1.0f + e);
}

__device__ __forceinline__ float sel4(const f32x4& v, int e) {
  // uniform-index select
  float a = (e & 1) ? v[1] : v[0];
  float b = (e & 1) ? v[3] : v[2];
  return (e & 2) ? b : a;
}

// ---- prep: W1[64][512] fp32 -> bf16 B-fragments, KC-MAJOR order ----
// frag id = kc*4 + nt (kc 0..15, nt 0..3): 64 lanes x 8 shorts each.
// Lane q=lane>>4, n=lane&15 holds W1[nt*16+n][kc*32 + q*8 + j], j=0..7.
// Chunk c (K=64) needs frag ids 8c..8c+7 = contiguous 8 KB.
__global__ __launch_bounds__(256) void w1_frag_prep(const float* __restrict__ W1,
                                                    short* __restrict__ ws) {
  const int g    = blockIdx.x * 256 + threadIdx.x;  // 0..4095
  const int lane = g & 63;
  const int idx  = g >> 6;                          // nt*16 + kc enumeration
  const int nt   = idx >> 4;
  const int kc   = idx & 15;
  const int n    = lane & 15;
  const int q    = lane >> 4;
  const float* wp = W1 + (size_t)(nt * 16 + n) * 512 + kc * 32 + q * 8;
  const float4 f0 = *(const float4*)wp;
  const float4 f1 = *(const float4*)(wp + 4);
  const float f[8] = {f0.x, f0.y, f0.z, f0.w, f1.x, f1.y, f1.z, f1.w};
  short* dst = ws + ((size_t)(kc * 4 + nt) * 64 + lane) * 8;
  #pragma unroll
  for (int j = 0; j < 8; j++) dst[j] = f2bf(f[j]);
}

__global__ __launch_bounds__(256, 4) void snn_fused(
    const float* __restrict__ x,  const short* __restrict__ w1f, const float* __restrict__ b1,
    const float* __restrict__ W2, const float* __restrict__ b2,
    const float* __restrict__ W3, const float* __restrict__ b3,
    const float* __restrict__ W4, const float* __restrict__ b4,
    float* __restrict__ out)
{
  __shared__ short xs[2][64][72];   // [buf][row][k] bf16, row stride 144 B; 18.4 KB
  __shared__ short wfb[2][4096];    // [buf][frag*512 + lane*8], 8 frags/chunk; 16 KB

  const int tid  = threadIdx.x;
  const int w    = tid >> 6;      // wave 0..3 <-> 16-row tile
  const int lane = tid & 63;
  const int rr   = lane >> 4;     // quad 0..3
  const int ll   = lane & 15;
  const int row0 = blockIdx.x * 64;

  // staging roles: thread -> (row r_st, 64-B segment s_st)
  const int r_st = tid >> 2;
  const int s_st = tid & 3;
  const float* xsrc = x + (size_t)(row0 + r_st) * 512 + s_st * 16;

  // ================= Phase 1: h_in = x @ W1^T + b1 =========================
  f32x4 acc[4];
  #pragma unroll
  for (int nt = 0; nt < 4; nt++) {
    const float bv = b1[nt * 16 + ll];
    f32x4 z = {bv, bv, bv, bv};
    acc[nt] = z;
  }

  // ---- prologue: stage chunk 0 ----
  {
    const float4 x0 = *(const float4*)(xsrc + 0);
    const float4 x1 = *(const float4*)(xsrc + 4);
    const float4 x2 = *(const float4*)(xsrc + 8);
    const float4 x3 = *(const float4*)(xsrc + 12);
    const uint4  w0 = *(const uint4*)(w1f + tid * 16);
    const uint4  w1 = *(const uint4*)(w1f + tid * 16 + 8);
    union { bf16x8 v; unsigned u4[4]; } P0, P1;
    P0.u4[0] = packbf(x0.y, x0.x); P0.u4[1] = packbf(x0.w, x0.z);
    P0.u4[2] = packbf(x1.y, x1.x); P0.u4[3] = packbf(x1.w, x1.z);
    P1.u4[0] = packbf(x2.y, x2.x); P1.u4[1] = packbf(x2.w, x2.z);
    P1.u4[2] = packbf(x3.y, x3.x); P1.u4[3] = packbf(x3.w, x3.z);
    *(bf16x8*)&xs[0][r_st][s_st * 16]     = P0.v;
    *(bf16x8*)&xs[0][r_st][s_st * 16 + 8] = P1.v;
    *(uint4*)&wfb[0][tid * 16]     = w0;
    *(uint4*)&wfb[0][tid * 16 + 8] = w1;
  }
  __syncthreads();

  #pragma unroll
  for (int c = 0; c < 8; c++) {
    const int cur = c & 1, nxt = cur ^ 1;
    // issue next-chunk global loads (cannot sink past the staging writes)
    float4 nx0, nx1, nx2, nx3; uint4 nw0, nw1;
    if (c < 7) {
      const float* xp = xsrc + (c + 1) * 64;
      nx0 = *(const float4*)(xp + 0);
      nx1 = *(const float4*)(xp + 4);
      nx2 = *(const float4*)(xp + 8);
      nx3 = *(const float4*)(xp + 12);
      const short* wp = w1f + (c + 1) * 4096 + tid * 16;
      nw0 = *(const uint4*)wp;
      nw1 = *(const uint4*)(wp + 8);
    }
    // compute current chunk from LDS
    #pragma unroll
    for (int kh = 0; kh < 2; kh++) {
      const bf16x8 A = *(const bf16x8*)&xs[cur][w * 16 + ll][kh * 32 + rr * 8];
      #pragma unroll
      for (int nt = 0; nt < 4; nt++) {
        const bf16x8 Bv = *(const bf16x8*)&wfb[cur][(kh * 4 + nt) * 512 + lane * 8];
        acc[nt] = __builtin_amdgcn_mfma_f32_16x16x32_bf16(A, Bv, acc[nt], 0, 0, 0);
      }
    }
    // convert + write staged data into the other buffer
    if (c < 7) {
      union { bf16x8 v; unsigned u4[4]; } P0, P1;
      P0.u4[0] = packbf(nx0.y, nx0.x); P0.u4[1] = packbf(nx0.w, nx0.z);
      P0.u4[2] = packbf(nx1.y, nx1.x); P0.u4[3] = packbf(nx1.w, nx1.z);
      P1.u4[0] = packbf(nx2.y, nx2.x); P1.u4[1] = packbf(nx2.w, nx2.z);
      P1.u4[2] = packbf(nx3.y, nx3.x); P1.u4[3] = packbf(nx3.w, nx3.z);
      *(bf16x8*)&xs[nxt][r_st][s_st * 16]     = P0.v;
      *(bf16x8*)&xs[nxt][r_st][s_st * 16 + 8] = P1.v;
      *(uint4*)&wfb[nxt][tid * 16]     = nw0;
      *(uint4*)&wfb[nxt][tid * 16 + 8] = nw1;
      __syncthreads();
    }
  }
  // C layout: col = ll (h within nt-tile), row = rr*4 + e.

  // ============ Phase A: closed-form spike-possibility test ================
  // Stepwise v1(t) can reach 1 only if h >= (256/255)*(1-1e-6) > 1.0038.
  unsigned rowneed = 0;   // wave-uniform 16-bit: local row r flagged
  #pragma unroll
  for (int e = 0; e < 4; e++) {
    const float mx = fmaxf(fmaxf(acc[0][e], acc[1][e]), fmaxf(acc[2][e], acc[3][e]));
    const ull bal = __ballot(mx >= 1.0038f);
    #pragma unroll
    for (int r2 = 0; r2 < 4; r2++)
      if ((bal >> (r2 * 16)) & 0xFFFFu) rowneed |= 1u << (r2 * 4 + e);
  }

  ull s3any = 0;
  ull m_lo = 0, m_hi = 0;   // spike masks: slot = t*16+r; slots 0..63 in m_lo
  if (rowneed) {
    // weights for the exact sim
    float w2r[16], w3r[16];
    #pragma unroll
    for (int jj = 0; jj < 4; jj++) {
      const float4 t2 = *(const float4*)(W2 + ll * 64 + rr * 16 + jj * 4);
      w2r[jj * 4 + 0] = t2.x; w2r[jj * 4 + 1] = t2.y;
      w2r[jj * 4 + 2] = t2.z; w2r[jj * 4 + 3] = t2.w;
      const float4 t3 = *(const float4*)(W3 + lane * 16 + jj * 4);
      w3r[jj * 4 + 0] = t3.x; w3r[jj * 4 + 1] = t3.y;
      w3r[jj * 4 + 2] = t3.z; w3r[jj * 4 + 3] = t3.w;
    }
    const float b2r = b2[ll];
    const float b3r = b3[lane];

    unsigned rn = rowneed;
    while (rn) {
      const int r = __builtin_ctz(rn); rn &= rn - 1;   // wave-uniform row
      // fetch h[row r][h=lane] from accumulators via bpermute
      const int e = r & 3;
      const int bidx = (((r >> 2) * 16) + ll) * 4;
      const float c0 = sel4(acc[0], e), c1 = sel4(acc[1], e);
      const float c2 = sel4(acc[2], e), c3 = sel4(acc[3], e);
      const float t0 = __uint_as_float(__builtin_amdgcn_ds_bpermute(bidx, __float_as_uint(c0)));
      const float t1 = __uint_as_float(__builtin_amdgcn_ds_bpermute(bidx, __float_as_uint(c1)));
      const float t2 = __uint_as_float(__builtin_amdgcn_ds_bpermute(bidx, __float_as_uint(c2)));
      const float t3 = __uint_as_float(__builtin_amdgcn_ds_bpermute(bidx, __float_as_uint(c3)));
      const float h = (lane < 32) ? ((lane < 16) ? t0 : t1)
                                  : ((lane < 48) ? t2 : t3);
      float v1 = 0.f, v2 = 0.f, v3 = 0.f;   // v2 replicated over quads
      for (int t = 0; t < TS; t++) {
        // --- LIF layer 1 (lane = h), exact stepwise ---
        v1 = v1 + (h - v1) * 0.5f;
        const bool s1 = v1 >= 1.0f;
        const ull m1 = __ballot(s1);
        if (s1) v1 = 0.f;
        // --- in2[l=ll] = b2 + sum_h s1[h]*W2[l][h], h split over quads ---
        float in2 = b2r;
        if (m1 != 0ULL) {
          const unsigned mb = (unsigned)(m1 >> (rr * 16)) & 0xFFFFu;
          float p = 0.f;
          #pragma unroll
          for (int j = 0; j < 16; j++) p += ((mb >> j) & 1u) ? w2r[j] : 0.f;
          p += __shfl_xor(p, 16);
          p += __shfl_xor(p, 32);
          in2 += p;
        }
        // --- LIF layer 2 (replicated across quads; ballot bits replicate) ---
        v2 = v2 + (in2 - v2) * 0.5f;
        const bool s2 = v2 >= 1.0f;
        const ull bm2 = __ballot(s2);
        if (s2) v2 = 0.f;
        const unsigned m2 = (unsigned)bm2 & 0xFFFFu;   // wave-uniform
        // --- in3[h=lane] = b3 + sum_l s2[l]*W3[h][l] ---
        float in3 = b3r;
        if (m2 != 0u) {
          float q = 0.f;
          #pragma unroll
          for (int j = 0; j < 16; j++) q += ((m2 >> j) & 1u) ? w3r[j] : 0.f;
          in3 += q;
        }
        // --- LIF layer 3 ---
        v3 = v3 + (in3 - v3) * 0.5f;
        const bool s3 = v3 >= 1.0f;
        const ull m3 = __ballot(s3);
        if (s3) v3 = 0.f;
        if (m3 != 0ULL) {
          s3any |= m3;
          const int slot = t * 16 + r;               // uniform
          const bool mine = (lane == (slot & 63));
          if (slot < 64) m_lo = mine ? m3 : m_lo;
          else           m_hi = mine ? m3 : m_hi;
        }
      }
    }
  }

  // ================= Phase B: out = mean_t sigmoid(s3 @ W4^T + b4) ==========
  if (s3any == 0ULL) {
    // Exact fast path: all s3 == 0 for this wave's 16 rows.
    const int cg = lane * 4;
    const float4 b4a = *(const float4*)(b4 + cg);
    const float4 b4b = *(const float4*)(b4 + 256 + cg);
    f32x4 sa, sb;
    sa[0] = sigmoid_fast(b4a.x); sa[1] = sigmoid_fast(b4a.y);
    sa[2] = sigmoid_fast(b4a.z); sa[3] = sigmoid_fast(b4a.w);
    sb[0] = sigmoid_fast(b4b.x); sb[1] = sigmoid_fast(b4b.y);
    sb[2] = sigmoid_fast(b4b.z); sb[3] = sigmoid_fast(b4b.w);
    #pragma unroll
    for (int r = 0; r < 16; r++) {
      float* rp = out + (size_t)(row0 + w * 16 + r) * 512;
      *(f32x4*)(rp + cg) = sa;
      *(f32x4*)(rp + 256 + cg) = sb;
    }
    return;
  }

  // ---- rare path: this wave's rows have s3 spikes; full MFMA over 512 cols ----
  // fetch this wave's 8 t-masks for row ll via bpermute
  ull mrow[TS];
  #pragma unroll
  for (int t = 0; t < TS; t++) {
    const ull msrc = (t < 4) ? m_lo : m_hi;
    const int pidx = (((t & 3) * 16) + ll) * 4;
    const unsigned lo32 = (unsigned)__builtin_amdgcn_ds_bpermute(pidx, (int)(unsigned)msrc);
    const unsigned hi32 = (unsigned)__builtin_amdgcn_ds_bpermute(pidx, (int)(unsigned)(msrc >> 32));
    mrow[t] = ((ull)hi32 << 32) | lo32;
  }

  for (int nt = 0; nt < 32; nt++) {
    const int dcol = nt * 16 + ll;
    const float bbv = b4[dcol];
    const float sigb = sigmoid_fast(bbv);
    bf16x8 Bf[2];
    #pragma unroll
    for (int c = 0; c < 2; c++) {
      const float* wp = W4 + (size_t)dcol * 64 + c * 32 + rr * 8;
      const float4 f0 = *(const float4*)wp;
      const float4 f1 = *(const float4*)(wp + 4);
      union { bf16x8 v; short s[8]; } u;
      u.s[0] = f2bf(f0.x); u.s[1] = f2bf(f0.y); u.s[2] = f2bf(f0.z); u.s[3] = f2bf(f0.w);
      u.s[4] = f2bf(f1.x); u.s[5] = f2bf(f1.y); u.s[6] = f2bf(f1.z); u.s[7] = f2bf(f1.w);
      Bf[c] = u.v;
    }
    f32x4 accv = {0.f, 0.f, 0.f, 0.f};
    for (int t = 0; t < TS; t++) {
      if (!__any((int)(mrow[t] != 0ULL))) {
        #pragma unroll
        for (int e = 0; e < 4; e++) accv[e] += sigb;
        continue;
      }
      const ull m = mrow[t];
      const unsigned byte0 = (unsigned)(m >> (rr * 8)) & 0xFFu;
      const unsigned byte1 = (unsigned)((m >> 32) >> (rr * 8)) & 0xFFu;
      union { bf16x8 v; unsigned u4[4]; } a0, a1;
      #pragma unroll
      for (int p2 = 0; p2 < 4; p2++) {
        a0.u4[p2] = ((byte0 >> (2 * p2)) & 1u) * 0x3F80u
                  + ((byte0 >> (2 * p2 + 1)) & 1u) * 0x3F800000u;
        a1.u4[p2] = ((byte1 >> (2 * p2)) & 1u) * 0x3F80u
                  + ((byte1 >> (2 * p2 + 1)) & 1u) * 0x3F800000u;
      }
      f32x4 z = {bbv, bbv, bbv, bbv};
      z = __builtin_amdgcn_mfma_f32_16x16x32_bf16(a0.v, Bf[0], z, 0, 0, 0);
      z = __builtin_amdgcn_mfma_f32_16x16x32_bf16(a1.v, Bf[1], z, 0, 0, 0);
      #pragma unroll
      for (int e = 0; e < 4; e++) accv[e] += sigmoid_fast(z[e]);
    }
    #pragma unroll
    for (int e = 0; e < 4; e++) {
      const int rloc = w * 16 + rr * 4 + e;
      out[(size_t)(row0 + rloc) * 512 + dcol] = accv[e] * 0.125f;
    }
  }
}

extern "C" void kernel_launch(void* const* d_in, const int* in_sizes, int n_in,
                              void* d_out, int out_size, void* d_ws, size_t ws_size,
                              hipStream_t stream) {
  const float* x  = (const float*)d_in[0];
  const float* W1 = (const float*)d_in[1];
  const float* b1 = (const float*)d_in[2];
  const float* W2 = (const float*)d_in[3];
  const float* b2 = (const float*)d_in[4];
  const float* W3 = (const float*)d_in[5];
  const float* b3 = (const float*)d_in[6];
  const float* W4 = (const float*)d_in[7];
  const float* b4 = (const float*)d_in[8];
  float* out = (float*)d_out;
  short* w1f = (short*)d_ws;     // 64 frag-units * 64 lanes * 8 shorts = 65536 B

  const int B = in_sizes[0] / 512;   // 65536
  const int nblocks = B / 64;        // 1024

  hipLaunchKernelGGL(w1_frag_prep, dim3(16), dim3(256), 0, stream, W1, w1f);
  hipLaunchKernelGGL(snn_fused, dim3(nblocks), dim3(256), 0, stream,
                     x, w1f, b1, W2, b2, W3, b3, W4, b4, out);
}